// Round 3
// baseline (423.176 us; speedup 1.0000x reference)
//
#include <hip/hip_runtime.h>
#include <stdint.h>

#define DIM 4096
#define NH 32
#define NKV 8
#define HD 128
#define SEQ 2048
#define KVD 1024  // NKV*HD

typedef unsigned short u16;
typedef __attribute__((ext_vector_type(8))) short bf16x8;   // 8 bf16 in 4 VGPRs
typedef __attribute__((ext_vector_type(4))) float f32x4;

__device__ __forceinline__ float bf2f(u16 v){
  union { unsigned u; float f; } c; c.u = ((unsigned)v) << 16; return c.f;
}
__device__ __forceinline__ u16 f2bf(float f){
  union { float f; unsigned u; } c; c.f = f;
  unsigned u = c.u;
  u += 0x7FFF + ((u >> 16) & 1);   // RNE
  return (u16)(u >> 16);
}
__device__ __forceinline__ unsigned pack2bf(float a, float b){
  return (unsigned)f2bf(a) | ((unsigned)f2bf(b) << 16);
}

__device__ __forceinline__ void gl_lds16(const void* g, void* l){
  __builtin_amdgcn_global_load_lds((const __attribute__((address_space(1))) void*)g,
                                   (__attribute__((address_space(3))) void*)l, 16, 0, 0);
}

#define VMCNT6 asm volatile("s_waitcnt vmcnt(6)" ::: "memory")
#define VMCNT0 asm volatile("s_waitcnt vmcnt(0)" ::: "memory")
#define BARRAW asm volatile("s_barrier" ::: "memory")

// ---------------- fp32 -> bf16 conversion (exact grids, sizes % 1024 == 0) ----
__global__ void cvt_bf16(const float* __restrict__ in, u16* __restrict__ out, int n){
  int i = (blockIdx.x*256 + threadIdx.x)*4;
  if (i + 3 >= n && i >= n) return;
  float4 v = *(const float4*)(in + i);
  ushort4 o;
  o.x = f2bf(v.x); o.y = f2bf(v.y); o.z = f2bf(v.z); o.w = f2bf(v.w);
  *(ushort4*)(out + i) = o;
}

// ---------------- 8-wave pipelined NT GEMM: C = A[M,K] * B[N,K]^T -------------
// BM=128, BN=256, BK=64. Triple-buffered LDS (144 KB), 2-tile-deep prefetch,
// ONE raw s_barrier + counted vmcnt(6) per K-tile (T3+T4), setprio around MFMA
// clusters (T5), XOR-swizzled LDS (T2 both-sides), XCD-aware bid swizzle (T1).
// EPI 0: fused QKV — bn<16: Q(+RoPE)->C0[2048][4096]; bn<20: K(+RoPE)->C1
//        [2048][1024]; else: V^T->C2[1024][2048].
// EPI 1: plain f32 C0[M][4096] (O projection).
template<int EPI>
__global__ __launch_bounds__(512, 2) void gemm8(const u16* __restrict__ A,
    const u16* __restrict__ B0, const u16* __restrict__ B1, const u16* __restrict__ B2,
    void* __restrict__ C0, void* __restrict__ C1, void* __restrict__ C2,
    const float* __restrict__ rf, int K){
  __shared__ __align__(16) char smA[3][16384];   // [128 rows][8 slots of 16B]
  __shared__ __align__(16) char smB[3][32768];   // [256 rows][8 slots of 16B]
  const int t = threadIdx.x, w = t >> 6, l = t & 63;
  const int lg = l >> 4, li = l & 15;
  const int nbx = gridDim.x;
  const int bid = (blockIdx.x & 7) * (nbx >> 3) + (blockIdx.x >> 3);   // XCD swizzle
  const int bm = bid & 15;          // M = 2048 -> 16 row-blocks; bn-major order
  const int bn = bid >> 4;
  const int wr = w >> 2, wc = w & 3;

  const u16* B;
  if (EPI == 0){
    if (bn < 16)      B = B0 + (size_t)bn*256*K;
    else if (bn < 20) B = B1 + (size_t)(bn-16)*256*K;
    else              B = B2 + (size_t)(bn-20)*256*K;
  } else {
    B = B0 + (size_t)bn*256*K;
  }
  const u16* Arow = A + (size_t)bm*128*K;

  // staging: chunk c = 64 slots = 8 rows; lane l -> row c*8+(l>>3), slot l&7
  auto stA = [&](int k0, int b, int c){
    const int row = c*8 + (l >> 3);
    const int col = ((l & 7) ^ (row & 7)) << 3;     // pre-swizzled source col
    gl_lds16(Arow + (size_t)row*K + k0 + col, &smA[b][c*1024]);
  };
  auto stB = [&](int k0, int b, int c){
    const int row = c*8 + (l >> 3);
    const int col = ((l & 7) ^ (row & 7)) << 3;
    gl_lds16(B + (size_t)row*K + k0 + col, &smB[b][c*1024]);
  };
  auto stage_full = [&](int kt, int b){
    const int k0 = kt*64;
    stA(k0, b, w); stA(k0, b, w+8);
    stB(k0, b, w); stB(k0, b, w+8); stB(k0, b, w+16); stB(k0, b, w+24);
  };

  f32x4 acc[4][4] = {};
  const int nt = K >> 6;

  auto body = [&](int tt){
    const int b = tt % 3;
    const int ps = tt + 2;
    const bool st = ps < nt;
    const int pb = ps % 3, k2 = ps*64;
    // ---- phase 0 (kk=0) ----
    if (st){ stA(k2, pb, w); stA(k2, pb, w+8); stB(k2, pb, w); }
    bf16x8 af[4], bfr[4];
    #pragma unroll
    for (int mi = 0; mi < 4; ++mi){
      const int Ra = wr*64 + mi*16 + li;
      af[mi] = *(const bf16x8*)&smA[b][(Ra*8 + (lg ^ (Ra & 7)))*16];
    }
    #pragma unroll
    for (int ni = 0; ni < 4; ++ni){
      const int Rb = wc*64 + ni*16 + li;
      bfr[ni] = *(const bf16x8*)&smB[b][(Rb*8 + (lg ^ (Rb & 7)))*16];
    }
    __builtin_amdgcn_s_setprio(1);
    #pragma unroll
    for (int mi = 0; mi < 4; ++mi)
      #pragma unroll
      for (int ni = 0; ni < 4; ++ni)
        acc[mi][ni] = __builtin_amdgcn_mfma_f32_16x16x32_bf16(af[mi], bfr[ni], acc[mi][ni], 0, 0, 0);
    __builtin_amdgcn_s_setprio(0);
    // ---- phase 1 (kk=1) ----
    if (st){ stB(k2, pb, w+8); stB(k2, pb, w+16); stB(k2, pb, w+24); }
    #pragma unroll
    for (int mi = 0; mi < 4; ++mi){
      const int Ra = wr*64 + mi*16 + li;
      af[mi] = *(const bf16x8*)&smA[b][(Ra*8 + ((lg+4) ^ (Ra & 7)))*16];
    }
    #pragma unroll
    for (int ni = 0; ni < 4; ++ni){
      const int Rb = wc*64 + ni*16 + li;
      bfr[ni] = *(const bf16x8*)&smB[b][(Rb*8 + ((lg+4) ^ (Rb & 7)))*16];
    }
    __builtin_amdgcn_s_setprio(1);
    #pragma unroll
    for (int mi = 0; mi < 4; ++mi)
      #pragma unroll
      for (int ni = 0; ni < 4; ++ni)
        acc[mi][ni] = __builtin_amdgcn_mfma_f32_16x16x32_bf16(af[mi], bfr[ni], acc[mi][ni], 0, 0, 0);
    __builtin_amdgcn_s_setprio(0);
  };

  stage_full(0, 0);
  stage_full(1, 1);
  for (int tt = 0; tt < nt - 1; ++tt){
    VMCNT6;            // tile tt landed; tile tt+1 (6 loads) may stay in flight
    BARRAW;            // all waves agree tile tt is fully staged
    body(tt);
  }
  VMCNT0;
  BARRAW;
  body(nt - 1);

  // ---------------- epilogue ----------------
  const int row0 = bm*128 + wr*64;
  if (EPI == 1){
    float* C = (float*)C0;
    const int col0 = bn*256 + wc*64;
    #pragma unroll
    for (int mi = 0; mi < 4; ++mi)
      #pragma unroll
      for (int ni = 0; ni < 4; ++ni)
        #pragma unroll
        for (int r = 0; r < 4; ++r)
          C[(size_t)(row0 + mi*16 + lg*4 + r)*DIM + col0 + ni*16 + li] = acc[mi][ni][r];
  } else {
    if (bn < 20){      // Q or K with fused RoPE
      u16* C = (bn < 16) ? (u16*)C0 : (u16*)C1;
      const int ldc = (bn < 16) ? DIM : KVD;
      const int cb  = ((bn < 16) ? bn*256 : (bn-16)*256) + wc*64;
      #pragma unroll
      for (int mi = 0; mi < 4; ++mi)
        #pragma unroll
        for (int ni = 0; ni < 4; ++ni){
          const int col = cb + ni*16 + li;
          const int i4 = ((col & 127) >> 1) << 2;
          #pragma unroll
          for (int r = 0; r < 4; ++r){
            const float v = acc[mi][ni][r];
            const float p = __shfl_xor(v, 1);          // partner col (li^1)
            const int srow = row0 + mi*16 + lg*4 + r;
            const float cs = rf[(size_t)srow*256 + i4];
            const float sn = rf[(size_t)srow*256 + i4 + 1];
            const float o = (col & 1) ? (v*cs + p*sn) : (v*cs - p*sn);
            C[(size_t)srow*ldc + col] = f2bf(o);
          }
        }
    } else {           // V -> transposed write Vt[1024][2048]
      u16* C = (u16*)C2;
      const int cb = (bn-20)*256 + wc*64;
      #pragma unroll
      for (int mi = 0; mi < 4; ++mi)
        #pragma unroll
        for (int ni = 0; ni < 4; ++ni){
          const int col = cb + ni*16 + li;
          const int sr0 = row0 + mi*16 + lg*4;
          ushort4 o;
          o.x = f2bf(acc[mi][ni][0]); o.y = f2bf(acc[mi][ni][1]);
          o.z = f2bf(acc[mi][ni][2]); o.w = f2bf(acc[mi][ni][3]);
          *(ushort4*)&C[(size_t)col*SEQ + sr0] = o;
        }
    }
  }
}

// ---------------- causal GQA flash attention ---------------------------------
// 1D grid 1024, longest-qt blocks first: qt = 31 - bid/32, h = bid%32.
// 4 waves; wave w owns q rows [qt*64+16w, +16). Swapped QK^T (mfma(K,Q)) so
// each lane owns one full q-row (q = li): in-lane softmax + 2-shfl reduce.
// K/V double-buffered in LDS, next tile staged before compute (2-phase T3).
__global__ __launch_bounds__(256) void flash_attn(const u16* __restrict__ Q,
                                                  const u16* __restrict__ Kg,
                                                  const u16* __restrict__ Vt,
                                                  u16* __restrict__ O){
  __shared__ bf16x8 smK[2][64*16];              // [64 rows][16 slots], swizzled; 2x16KB
  __shared__ bf16x8 smV[2][128*8];              // [128 rows][8 slots], swizzled; 2x16KB
  __shared__ __align__(16) u16 smP[4][16*64];   // per-wave P, XOR-swizzled 16B chunks; 8KB
  const int bid = blockIdx.x;
  const int h  = bid & 31;
  const int qt = 31 - (bid >> 5);
  const int g  = h >> 2;
  const int t = threadIdx.x, w = t >> 6, l = t & 63;
  const int lg = l >> 4, li = l & 15;

  bf16x8 qf[4];                                  // Q row (w*16+li), d-chunks
  {
    const u16* qrow = Q + (size_t)(qt*64 + w*16 + li)*DIM + h*HD;
    #pragma unroll
    for (int kc = 0; kc < 4; ++kc)
      qf[kc] = *(const bf16x8*)(qrow + kc*32 + lg*8);
  }
  f32x4 accO[8] = {};
  float mrun = -1e30f, lsum = 0.f;
  const float SC = 0.08838834764831845f * 1.4426950408889634f;  // scale * log2(e)

  const int ksrow = t >> 4, ksslot = t & 15;  // K staging: 256B rows, 16 slots
  const int vsrow = t >> 3, vsslot = t & 7;   // V staging: 128B rows, 8 slots

  auto stage = [&](int kt, int b){
    #pragma unroll
    for (int j = 0; j < 4; ++j){
      const int krow = j*16 + ksrow;
      const int ksl = (ksslot & 8) | ((ksslot ^ (krow & 7)) & 7);
      gl_lds16(Kg + (size_t)(kt*64 + krow)*KVD + g*HD + ksl*8, (char*)&smK[b][0] + j*4096 + w*1024);
      const int vrow = j*32 + vsrow;
      const int vsl = (vsslot ^ (vrow & 7)) & 7;
      gl_lds16(Vt + (size_t)(g*HD + vrow)*SEQ + kt*64 + vsl*8, (char*)&smV[b][0] + j*4096 + w*1024);
    }
  };

  stage(0, 0);
  int buf = 0;
  u16* pw = &smP[w][0];

  for (int kt = 0; kt <= qt; ++kt){
    __syncthreads();                      // implicit vmcnt(0): tile-kt stage done
    if (kt < qt) stage(kt + 1, buf ^ 1);  // overlap next stage with this compute

    // S^T = K Q^T : lane holds S[kk = nj*16+lg*4+r][q = li]
    f32x4 sacc[4] = {};
    #pragma unroll
    for (int kc = 0; kc < 4; ++kc){
      #pragma unroll
      for (int nj = 0; nj < 4; ++nj){
        const int R = nj*16 + li;
        int sl = lg + 4*kc;
        sl = (sl & 8) | ((sl ^ (R & 7)) & 7);
        sacc[nj] = __builtin_amdgcn_mfma_f32_16x16x32_bf16(smK[buf][R*16 + sl], qf[kc], sacc[nj], 0, 0, 0);
      }
    }
    float p[4][4];
    #pragma unroll
    for (int nj = 0; nj < 4; ++nj)
      #pragma unroll
      for (int r = 0; r < 4; ++r)
        p[nj][r] = sacc[nj][r] * SC;
    if (kt == qt){                         // mask only on the diagonal tile
      const int qloc = w*16 + li;
      #pragma unroll
      for (int nj = 0; nj < 4; ++nj)
        #pragma unroll
        for (int r = 0; r < 4; ++r)
          if (nj*16 + lg*4 + r > qloc) p[nj][r] = -1e30f;
    }
    // online softmax, row q=li fully in this lane (16 vals) + lanes l^16,l^32
    float mx = p[0][0];
    #pragma unroll
    for (int nj = 0; nj < 4; ++nj)
      #pragma unroll
      for (int r = 0; r < 4; ++r) mx = fmaxf(mx, p[nj][r]);
    mx = fmaxf(mx, __shfl_xor(mx, 16));
    mx = fmaxf(mx, __shfl_xor(mx, 32));
    const float mnew = fmaxf(mrun, mx);
    const float alpha = exp2f(mrun - mnew);
    float s = 0.f;
    #pragma unroll
    for (int nj = 0; nj < 4; ++nj)
      #pragma unroll
      for (int r = 0; r < 4; ++r){ p[nj][r] = exp2f(p[nj][r] - mnew); s += p[nj][r]; }
    s += __shfl_xor(s, 16);
    s += __shfl_xor(s, 32);
    lsum = lsum * alpha + s;
    mrun = mnew;
    // broadcast alpha to accO's rows (q = lg*4+r held by lane li' = lg*4+r)
    float al[4];
    #pragma unroll
    for (int r = 0; r < 4; ++r) al[r] = __shfl(alpha, (l & 48) | (lg*4 + r));
    #pragma unroll
    for (int dj = 0; dj < 8; ++dj)
      #pragma unroll
      for (int r = 0; r < 4; ++r) accO[dj][r] *= al[r];
    // write P (row q=li, kk consecutive per write): 4x 8B swizzled ds_write
    #pragma unroll
    for (int nj = 0; nj < 4; ++nj){
      const int c = nj*2 + (lg >> 1);
      uint2 v; v.x = pack2bf(p[nj][0], p[nj][1]); v.y = pack2bf(p[nj][2], p[nj][3]);
      *(uint2*)((char*)pw + li*128 + ((c ^ (li & 7)) << 4) + ((lg & 1) << 3)) = v;
    }
    // O += P V   (A-frag: P row li, kk = kc2*32+lg*8+j; B-frag: Vt row d)
    #pragma unroll
    for (int kc2 = 0; kc2 < 2; ++kc2){
      const bf16x8 pf = *(const bf16x8*)((char*)pw + li*128 + (((kc2*4 + lg) ^ (li & 7)) << 4));
      #pragma unroll
      for (int dj = 0; dj < 8; ++dj){
        const int R = dj*16 + li;
        const bf16x8 vf = smV[buf][R*8 + ((lg + 4*kc2) ^ (R & 7))];
        accO[dj] = __builtin_amdgcn_mfma_f32_16x16x32_bf16(pf, vf, accO[dj], 0, 0, 0);
      }
    }
    buf ^= 1;
  }
  // epilogue: divide by row sum (row q=lg*4+r), write
  float linv[4];
  #pragma unroll
  for (int r = 0; r < 4; ++r) linv[r] = 1.f / __shfl(lsum, (l & 48) | (lg*4 + r));
  #pragma unroll
  for (int dj = 0; dj < 8; ++dj)
    #pragma unroll
    for (int r = 0; r < 4; ++r)
      O[(size_t)(qt*64 + w*16 + lg*4 + r)*DIM + h*HD + dj*16 + li] = f2bf(accO[dj][r] * linv[r]);
}

// -----------------------------------------------------------------------------
extern "C" void kernel_launch(void* const* d_in, const int* in_sizes, int n_in,
                              void* d_out, int out_size, void* d_ws, size_t ws_size,
                              hipStream_t stream){
  const float* x  = (const float*)d_in[0];
  const float* wq = (const float*)d_in[1];
  const float* wk = (const float*)d_in[2];
  const float* wv = (const float*)d_in[3];
  const float* wo = (const float*)d_in[4];
  const float* rf = (const float*)d_in[5];
  // d_in[6] = start_pos (unused by the reference)
  float* out = (float*)d_out;

  char* ws = (char*)d_ws;
  size_t off = 0;
  auto alloc = [&](size_t nbytes){ void* p = ws + off; off += (nbytes + 255) & ~(size_t)255; return p; };
  u16* xb  = (u16*)alloc((size_t)SEQ*DIM*2);
  u16* wqb = (u16*)alloc((size_t)DIM*DIM*2);
  u16* wkb = (u16*)alloc((size_t)KVD*DIM*2);
  u16* wvb = (u16*)alloc((size_t)KVD*DIM*2);
  u16* wob = (u16*)alloc((size_t)DIM*DIM*2);
  u16* Qb  = (u16*)alloc((size_t)SEQ*DIM*2);
  u16* K8  = (u16*)alloc((size_t)SEQ*KVD*2);
  u16* Vtr = (u16*)alloc((size_t)KVD*SEQ*2);
  u16* AO  = (u16*)alloc((size_t)SEQ*DIM*2);

  cvt_bf16<<<SEQ*DIM/1024, 256, 0, stream>>>(x,  xb,  SEQ*DIM);
  cvt_bf16<<<DIM*DIM/1024, 256, 0, stream>>>(wq, wqb, DIM*DIM);
  cvt_bf16<<<KVD*DIM/1024, 256, 0, stream>>>(wk, wkb, KVD*DIM);
  cvt_bf16<<<KVD*DIM/1024, 256, 0, stream>>>(wv, wvb, KVD*DIM);
  cvt_bf16<<<DIM*DIM/1024, 256, 0, stream>>>(wo, wob, DIM*DIM);

  // Fused QKV projection + RoPE + V^T: N = 4096(Q) + 1024(K) + 1024(V)
  // grid = 16 bm-blocks x 24 bn-blocks, bn-major for weight-panel L2 reuse
  gemm8<0><<<16*24, 512, 0, stream>>>(xb, wqb, wkb, wvb, Qb, K8, Vtr, rf, DIM);

  flash_attn<<<SEQ/64 * NH, 256, 0, stream>>>(Qb, K8, Vtr, AO);

  // O projection -> f32 out
  gemm8<1><<<16*16, 512, 0, stream>>>(AO, wob, nullptr, nullptr, out, nullptr, nullptr, nullptr, DIM);
}

// Round 4
// 334.381 us; speedup vs baseline: 1.2655x; 1.2655x over previous
//
#include <hip/hip_runtime.h>
#include <stdint.h>

#define DIM 4096
#define NH 32
#define NKV 8
#define HD 128
#define SEQ 2048
#define KVD 1024  // NKV*HD

typedef unsigned short u16;
typedef __attribute__((ext_vector_type(8))) short bf16x8;   // 8 bf16 in 4 VGPRs
typedef __attribute__((ext_vector_type(4))) float f32x4;

__device__ __forceinline__ float bf2f(u16 v){
  union { unsigned u; float f; } c; c.u = ((unsigned)v) << 16; return c.f;
}
__device__ __forceinline__ u16 f2bf(float f){
  union { float f; unsigned u; } c; c.f = f;
  unsigned u = c.u;
  u += 0x7FFF + ((u >> 16) & 1);   // RNE
  return (u16)(u >> 16);
}
__device__ __forceinline__ unsigned pack2bf(float a, float b){
  return (unsigned)f2bf(a) | ((unsigned)f2bf(b) << 16);
}

__device__ __forceinline__ void gl_lds16(const void* g, void* l){
  __builtin_amdgcn_global_load_lds((const __attribute__((address_space(1))) void*)g,
                                   (__attribute__((address_space(3))) void*)l, 16, 0, 0);
}

#define VM4 asm volatile("s_waitcnt vmcnt(4)" ::: "memory")
#define VM0 asm volatile("s_waitcnt vmcnt(0)" ::: "memory")
#define BAR __builtin_amdgcn_s_barrier()

// ---------------- fused fp32 -> bf16 conversion (one launch, 5 segments) -----
__global__ void cvt_all(const float* __restrict__ x,  const float* __restrict__ wq,
                        const float* __restrict__ wk, const float* __restrict__ wv,
                        const float* __restrict__ wo,
                        u16* __restrict__ xb,  u16* __restrict__ wqb,
                        u16* __restrict__ wkb, u16* __restrict__ wvb,
                        u16* __restrict__ wob){
  const int b = blockIdx.x;
  const float* in; u16* out; int base;
  if      (b <  8192){ in = x;  out = xb;  base = b; }
  else if (b < 24576){ in = wq; out = wqb; base = b - 8192; }
  else if (b < 28672){ in = wk; out = wkb; base = b - 24576; }
  else if (b < 32768){ in = wv; out = wvb; base = b - 28672; }
  else               { in = wo; out = wob; base = b - 32768; }
  const int i = (base*256 + threadIdx.x)*4;
  float4 v = *(const float4*)(in + i);
  ushort4 o;
  o.x = f2bf(v.x); o.y = f2bf(v.y); o.z = f2bf(v.z); o.w = f2bf(v.w);
  *(ushort4*)(out + i) = o;
}

// ---------------- out += partial (f32x4, exact grid) --------------------------
__global__ void add_f32(float* __restrict__ out, const float* __restrict__ p){
  const int i = blockIdx.x*256 + threadIdx.x;
  float4 a = ((const float4*)out)[i];
  const float4 b = ((const float4*)p)[i];
  a.x += b.x; a.y += b.y; a.z += b.z; a.w += b.w;
  ((float4*)out)[i] = a;
}

// ---------------- 256x256 4-phase pipelined NT GEMM ---------------------------
// BM=BN=256, BK=64, 8 waves (2x4), 128 KB dbuf LDS, K=4096 (DIM) always.
// Per K-tile: 4 phases; each: counted vmcnt(4) -> s_barrier -> stage one
// half-tile (2 gl_lds/thread) -> ds_read one C-quadrant -> setprio'd 16 MFMA.
// Stage order A0,B0,A1,B1 matches quadrant need order Qa,Qc,Qb,Qd. Loads never
// drain to 0 in the main loop (T3+T4); T2 swizzle both-sides; T1 XCD swizzle.
// EPI 0: fused QKV (idx = 8bm x 24bn): bn<16 Q+RoPE; bn<20 K+RoPE; else V^T.
// EPI 1: O-proj split-K (idx = 8bm x 2ks x 16bn): f32 partial to C0/C1.
template<int EPI>
__global__ __launch_bounds__(512, 2) void gemm256(const u16* __restrict__ A,
    const u16* __restrict__ B0, const u16* __restrict__ B1, const u16* __restrict__ B2,
    void* __restrict__ C0, void* __restrict__ C1, void* __restrict__ C2,
    const float* __restrict__ rf){
  __shared__ __align__(16) char lds[131072];   // A: [2][256][128B]  B: +65536
  const int t = threadIdx.x, w = t >> 6, l = t & 63;
  const int lg = l >> 4, li = l & 15;
  const int wr = w >> 2, wc = w & 3;
  const int nwg = gridDim.x;
  const int idx = ((int)blockIdx.x & 7)*(nwg >> 3) + ((int)blockIdx.x >> 3);

  int bm, bn, kbase, nt, ks = 0;
  const u16 *Ab, *Bb;
  if (EPI == 0){
    bm = idx & 7; bn = idx >> 3;                 // 8 x 24
    kbase = 0; nt = 64;
    Ab = A + (size_t)bm*256*DIM;
    Bb = (bn < 16) ? B0 + (size_t)bn*256*DIM
       : (bn < 20) ? B1 + (size_t)(bn-16)*256*DIM
                   : B2 + (size_t)(bn-20)*256*DIM;
  } else {
    bm = idx & 7; ks = (idx >> 3) & 1; bn = idx >> 4;   // 8 x 2 x 16
    kbase = ks*2048; nt = 32;
    Ab = A + (size_t)bm*256*DIM;
    Bb = B0 + (size_t)bn*256*DIM;
  }

  // stage one half-tile (128 rows x 64 cols of one matrix): 2 gl_lds / thread
  auto stHalf = [&](const u16* P, int rowbase, int kabs, int ldsoff){
    #pragma unroll
    for (int jj = 0; jj < 2; ++jj){
      const int rloc = jj*64 + (t >> 3);
      const int row  = rowbase + rloc;
      gl_lds16(P + (size_t)row*DIM + kabs + (((t & 7) ^ (row & 7)) << 3),
               lds + ldsoff + rloc*128 + (t & 7)*16);
    }
  };

  f32x4 acc[8][4] = {};

// one C-quadrant (m-half H, n-half G): 12 ds_read_b128 + 16 MFMA
#define PHASE(H, G) { \
    bf16x8 a_[4][2], b_[2][2]; \
    _Pragma("unroll") \
    for (int i2 = 0; i2 < 4; ++i2){ \
      const int R = (H)*128 + wr*64 + i2*16 + li; \
      a_[i2][0] = *(const bf16x8*)(ldsA + R*128 + (( lg    ^ (R & 7)) << 4)); \
      a_[i2][1] = *(const bf16x8*)(ldsA + R*128 + (((lg+4) ^ (R & 7)) << 4)); \
    } \
    _Pragma("unroll") \
    for (int j2 = 0; j2 < 2; ++j2){ \
      const int R = (G)*128 + wc*32 + j2*16 + li; \
      b_[j2][0] = *(const bf16x8*)(ldsB + R*128 + (( lg    ^ (R & 7)) << 4)); \
      b_[j2][1] = *(const bf16x8*)(ldsB + R*128 + (((lg+4) ^ (R & 7)) << 4)); \
    } \
    __builtin_amdgcn_s_setprio(1); \
    _Pragma("unroll") \
    for (int i2 = 0; i2 < 4; ++i2) \
      _Pragma("unroll") \
      for (int j2 = 0; j2 < 2; ++j2){ \
        acc[(H)*4+i2][(G)*2+j2] = __builtin_amdgcn_mfma_f32_16x16x32_bf16(a_[i2][0], b_[j2][0], acc[(H)*4+i2][(G)*2+j2], 0, 0, 0); \
        acc[(H)*4+i2][(G)*2+j2] = __builtin_amdgcn_mfma_f32_16x16x32_bf16(a_[i2][1], b_[j2][1], acc[(H)*4+i2][(G)*2+j2], 0, 0, 0); \
      } \
    __builtin_amdgcn_s_setprio(0); \
  }

  // prologue: stage tile 0 fully (A0,B0,A1,B1 = 8 loads/thread)
  stHalf(Ab,   0, kbase,         0);
  stHalf(Bb,   0, kbase, 65536    );
  stHalf(Ab, 128, kbase,     16384);
  stHalf(Bb, 128, kbase, 65536+16384);

  for (int tt = 0; tt < nt; ++tt){
    const int buf = tt & 1, b2 = buf ^ 1;
    const int k1 = kbase + (tt+1)*64;
    const bool pf = (tt + 1 < nt);
    const char* ldsA = lds + buf*32768;
    const char* ldsB = lds + 65536 + buf*32768;
    const int a2 = b2*32768, bo2 = 65536 + b2*32768;

    if (pf) VM4; else VM0;          // A0,B0 of tile tt landed
    BAR;
    if (pf) stHalf(Ab, 0, k1, a2);
    PHASE(0, 0)                     // Qa: A0,B0
    if (pf) VM4;                    // A1 of tile tt landed
    BAR;
    if (pf) stHalf(Bb, 0, k1, bo2);
    PHASE(1, 0)                     // Qc: A1,B0
    if (pf) VM4;                    // B1 of tile tt landed
    BAR;
    if (pf) stHalf(Ab, 128, k1, a2 + 16384);
    PHASE(0, 1)                     // Qb: A0,B1
    if (pf) stHalf(Bb, 128, k1, bo2 + 16384);
    PHASE(1, 1)                     // Qd: A1,B1 (already landed)
  }
#undef PHASE

  // ---------------- epilogue ----------------
  if (EPI == 1){
    float* C = (float*)(ks ? C1 : C0);
    #pragma unroll
    for (int i = 0; i < 8; ++i){
      const int srow = bm*256 + ((i < 4) ? wr*64 + i*16 : 128 + wr*64 + (i-4)*16) + lg*4;
      #pragma unroll
      for (int j = 0; j < 4; ++j){
        const int col = bn*256 + ((j < 2) ? wc*32 + j*16 : 128 + wc*32 + (j-2)*16) + li;
        #pragma unroll
        for (int r = 0; r < 4; ++r)
          C[(size_t)(srow + r)*DIM + col] = acc[i][j][r];
      }
    }
  } else {
    if (bn < 20){      // Q or K with fused RoPE
      u16* C = (bn < 16) ? (u16*)C0 : (u16*)C1;
      const int ldc = (bn < 16) ? DIM : KVD;
      const int cb  = (bn < 16) ? bn*256 : (bn-16)*256;
      #pragma unroll
      for (int i = 0; i < 8; ++i){
        const int srow0 = bm*256 + ((i < 4) ? wr*64 + i*16 : 128 + wr*64 + (i-4)*16) + lg*4;
        #pragma unroll
        for (int j = 0; j < 4; ++j){
          const int col = cb + ((j < 2) ? wc*32 + j*16 : 128 + wc*32 + (j-2)*16) + li;
          const int i4 = ((col & 127) >> 1) << 2;
          #pragma unroll
          for (int r = 0; r < 4; ++r){
            const float v = acc[i][j][r];
            const float p = __shfl_xor(v, 1);            // partner col (li^1)
            const int srow = srow0 + r;
            const float cs = rf[(size_t)srow*256 + i4];
            const float sn = rf[(size_t)srow*256 + i4 + 1];
            const float o = (col & 1) ? (v*cs + p*sn) : (v*cs - p*sn);
            C[(size_t)srow*ldc + col] = f2bf(o);
          }
        }
      }
    } else {           // V -> transposed write Vt[1024][2048]
      u16* C = (u16*)C2;
      const int cb = (bn - 20)*256;
      #pragma unroll
      for (int i = 0; i < 8; ++i){
        const int srow0 = bm*256 + ((i < 4) ? wr*64 + i*16 : 128 + wr*64 + (i-4)*16) + lg*4;
        #pragma unroll
        for (int j = 0; j < 4; ++j){
          const int col = cb + ((j < 2) ? wc*32 + j*16 : 128 + wc*32 + (j-2)*16) + li;
          ushort4 o;
          o.x = f2bf(acc[i][j][0]); o.y = f2bf(acc[i][j][1]);
          o.z = f2bf(acc[i][j][2]); o.w = f2bf(acc[i][j][3]);
          *(ushort4*)&C[(size_t)col*SEQ + srow0] = o;
        }
      }
    }
  }
}

// ---------------- causal GQA flash attention ---------------------------------
// 1D grid 1024, longest-qt blocks first: qt = 31 - bid/32, h = bid%32.
// 4 waves; wave w owns q rows [qt*64+16w, +16). Swapped QK^T (mfma(K,Q)) so
// each lane owns one full q-row (q = li): in-lane softmax + 2-shfl reduce.
// K/V double-buffered in LDS, next tile staged before compute (2-phase T3).
__global__ __launch_bounds__(256) void flash_attn(const u16* __restrict__ Q,
                                                  const u16* __restrict__ Kg,
                                                  const u16* __restrict__ Vt,
                                                  u16* __restrict__ O){
  __shared__ bf16x8 smK[2][64*16];              // [64 rows][16 slots], swizzled; 2x16KB
  __shared__ bf16x8 smV[2][128*8];              // [128 rows][8 slots], swizzled; 2x16KB
  __shared__ __align__(16) u16 smP[4][16*64];   // per-wave P, XOR-swizzled 16B chunks; 8KB
  const int bid = blockIdx.x;
  const int h  = bid & 31;
  const int qt = 31 - (bid >> 5);
  const int g  = h >> 2;
  const int t = threadIdx.x, w = t >> 6, l = t & 63;
  const int lg = l >> 4, li = l & 15;

  bf16x8 qf[4];                                  // Q row (w*16+li), d-chunks
  {
    const u16* qrow = Q + (size_t)(qt*64 + w*16 + li)*DIM + h*HD;
    #pragma unroll
    for (int kc = 0; kc < 4; ++kc)
      qf[kc] = *(const bf16x8*)(qrow + kc*32 + lg*8);
  }
  f32x4 accO[8] = {};
  float mrun = -1e30f, lsum = 0.f;
  const float SC = 0.08838834764831845f * 1.4426950408889634f;  // scale * log2(e)

  const int ksrow = t >> 4, ksslot = t & 15;  // K staging: 256B rows, 16 slots
  const int vsrow = t >> 3, vsslot = t & 7;   // V staging: 128B rows, 8 slots

  auto stage = [&](int kt, int b){
    #pragma unroll
    for (int j = 0; j < 4; ++j){
      const int krow = j*16 + ksrow;
      const int ksl = (ksslot & 8) | ((ksslot ^ (krow & 7)) & 7);
      gl_lds16(Kg + (size_t)(kt*64 + krow)*KVD + g*HD + ksl*8, (char*)&smK[b][0] + j*4096 + w*1024);
      const int vrow = j*32 + vsrow;
      const int vsl = (vsslot ^ (vrow & 7)) & 7;
      gl_lds16(Vt + (size_t)(g*HD + vrow)*SEQ + kt*64 + vsl*8, (char*)&smV[b][0] + j*4096 + w*1024);
    }
  };

  stage(0, 0);
  int buf = 0;
  u16* pw = &smP[w][0];

  for (int kt = 0; kt <= qt; ++kt){
    __syncthreads();                      // implicit vmcnt(0): tile-kt stage done
    if (kt < qt) stage(kt + 1, buf ^ 1);  // overlap next stage with this compute

    // S^T = K Q^T : lane holds S[kk = nj*16+lg*4+r][q = li]
    f32x4 sacc[4] = {};
    #pragma unroll
    for (int kc = 0; kc < 4; ++kc){
      #pragma unroll
      for (int nj = 0; nj < 4; ++nj){
        const int R = nj*16 + li;
        int sl = lg + 4*kc;
        sl = (sl & 8) | ((sl ^ (R & 7)) & 7);
        sacc[nj] = __builtin_amdgcn_mfma_f32_16x16x32_bf16(smK[buf][R*16 + sl], qf[kc], sacc[nj], 0, 0, 0);
      }
    }
    float p[4][4];
    #pragma unroll
    for (int nj = 0; nj < 4; ++nj)
      #pragma unroll
      for (int r = 0; r < 4; ++r)
        p[nj][r] = sacc[nj][r] * SC;
    if (kt == qt){                         // mask only on the diagonal tile
      const int qloc = w*16 + li;
      #pragma unroll
      for (int nj = 0; nj < 4; ++nj)
        #pragma unroll
        for (int r = 0; r < 4; ++r)
          if (nj*16 + lg*4 + r > qloc) p[nj][r] = -1e30f;
    }
    // online softmax, row q=li fully in this lane (16 vals) + lanes l^16,l^32
    float mx = p[0][0];
    #pragma unroll
    for (int nj = 0; nj < 4; ++nj)
      #pragma unroll
      for (int r = 0; r < 4; ++r) mx = fmaxf(mx, p[nj][r]);
    mx = fmaxf(mx, __shfl_xor(mx, 16));
    mx = fmaxf(mx, __shfl_xor(mx, 32));
    const float mnew = fmaxf(mrun, mx);
    const float alpha = exp2f(mrun - mnew);
    float s = 0.f;
    #pragma unroll
    for (int nj = 0; nj < 4; ++nj)
      #pragma unroll
      for (int r = 0; r < 4; ++r){ p[nj][r] = exp2f(p[nj][r] - mnew); s += p[nj][r]; }
    s += __shfl_xor(s, 16);
    s += __shfl_xor(s, 32);
    lsum = lsum * alpha + s;
    mrun = mnew;
    // broadcast alpha to accO's rows (q = lg*4+r held by lane li' = lg*4+r)
    float al[4];
    #pragma unroll
    for (int r = 0; r < 4; ++r) al[r] = __shfl(alpha, (l & 48) | (lg*4 + r));
    #pragma unroll
    for (int dj = 0; dj < 8; ++dj)
      #pragma unroll
      for (int r = 0; r < 4; ++r) accO[dj][r] *= al[r];
    // write P (row q=li, kk consecutive per write): 4x 8B swizzled ds_write
    #pragma unroll
    for (int nj = 0; nj < 4; ++nj){
      const int c = nj*2 + (lg >> 1);
      uint2 v; v.x = pack2bf(p[nj][0], p[nj][1]); v.y = pack2bf(p[nj][2], p[nj][3]);
      *(uint2*)((char*)pw + li*128 + ((c ^ (li & 7)) << 4) + ((lg & 1) << 3)) = v;
    }
    // O += P V   (A-frag: P row li, kk = kc2*32+lg*8+j; B-frag: Vt row d)
    #pragma unroll
    for (int kc2 = 0; kc2 < 2; ++kc2){
      const bf16x8 pf = *(const bf16x8*)((char*)pw + li*128 + (((kc2*4 + lg) ^ (li & 7)) << 4));
      #pragma unroll
      for (int dj = 0; dj < 8; ++dj){
        const int R = dj*16 + li;
        const bf16x8 vf = smV[buf][R*8 + ((lg + 4*kc2) ^ (R & 7))];
        accO[dj] = __builtin_amdgcn_mfma_f32_16x16x32_bf16(pf, vf, accO[dj], 0, 0, 0);
      }
    }
    buf ^= 1;
  }
  // epilogue: divide by row sum (row q=lg*4+r), write
  float linv[4];
  #pragma unroll
  for (int r = 0; r < 4; ++r) linv[r] = 1.f / __shfl(lsum, (l & 48) | (lg*4 + r));
  #pragma unroll
  for (int dj = 0; dj < 8; ++dj)
    #pragma unroll
    for (int r = 0; r < 4; ++r)
      O[(size_t)(qt*64 + w*16 + lg*4 + r)*DIM + h*HD + dj*16 + li] = f2bf(accO[dj][r] * linv[r]);
}

// -----------------------------------------------------------------------------
extern "C" void kernel_launch(void* const* d_in, const int* in_sizes, int n_in,
                              void* d_out, int out_size, void* d_ws, size_t ws_size,
                              hipStream_t stream){
  const float* x  = (const float*)d_in[0];
  const float* wq = (const float*)d_in[1];
  const float* wk = (const float*)d_in[2];
  const float* wv = (const float*)d_in[3];
  const float* wo = (const float*)d_in[4];
  const float* rf = (const float*)d_in[5];
  // d_in[6] = start_pos (unused by the reference)
  float* out = (float*)d_out;

  char* ws = (char*)d_ws;
  size_t off = 0;
  auto alloc = [&](size_t nbytes){ void* p = ws + off; off += (nbytes + 255) & ~(size_t)255; return p; };
  u16* xb  = (u16*)alloc((size_t)SEQ*DIM*2);
  u16* wqb = (u16*)alloc((size_t)DIM*DIM*2);
  u16* wkb = (u16*)alloc((size_t)KVD*DIM*2);
  u16* wvb = (u16*)alloc((size_t)KVD*DIM*2);
  u16* wob = (u16*)alloc((size_t)DIM*DIM*2);
  u16* Qb  = (u16*)alloc((size_t)SEQ*DIM*2);
  u16* K8  = (u16*)alloc((size_t)SEQ*KVD*2);
  u16* Vtr = (u16*)alloc((size_t)KVD*SEQ*2);
  u16* AO  = (u16*)alloc((size_t)SEQ*DIM*2);
  float* P1 = (float*)wqb;   // reuse: wqb is dead after the QKV GEMM (32 MB)

  cvt_all<<<49152, 256, 0, stream>>>(x, wq, wk, wv, wo, xb, wqb, wkb, wvb, wob);

  // Fused QKV projection + RoPE + V^T (192 blocks = 8bm x 24bn)
  gemm256<0><<<192, 512, 0, stream>>>(xb, wqb, wkb, wvb, Qb, K8, Vtr, rf);

  flash_attn<<<SEQ/64 * NH, 256, 0, stream>>>(Qb, K8, Vtr, AO);

  // O projection, split-K=2 (256 blocks): partial ks=0 -> out, ks=1 -> P1
  gemm256<1><<<256, 512, 0, stream>>>(AO, wob, nullptr, nullptr, out, P1, nullptr, nullptr);
  add_f32<<<8192, 256, 0, stream>>>(out, P1);
}

// Round 5
// 314.514 us; speedup vs baseline: 1.3455x; 1.0632x over previous
//
#include <hip/hip_runtime.h>
#include <stdint.h>

#define DIM 4096
#define NH 32
#define NKV 8
#define HD 128
#define SEQ 2048
#define KVD 1024  // NKV*HD

typedef unsigned short u16;
typedef __attribute__((ext_vector_type(8))) short bf16x8;   // 8 bf16 in 4 VGPRs
typedef __attribute__((ext_vector_type(4))) float f32x4;

__device__ __forceinline__ float bf2f(u16 v){
  union { unsigned u; float f; } c; c.u = ((unsigned)v) << 16; return c.f;
}
__device__ __forceinline__ u16 f2bf(float f){
  union { float f; unsigned u; } c; c.f = f;
  unsigned u = c.u;
  u += 0x7FFF + ((u >> 16) & 1);   // RNE
  return (u16)(u >> 16);
}
__device__ __forceinline__ unsigned pack2bf(float a, float b){
  return (unsigned)f2bf(a) | ((unsigned)f2bf(b) << 16);
}

__device__ __forceinline__ void gl_lds16(const void* g, void* l){
  __builtin_amdgcn_global_load_lds((const __attribute__((address_space(1))) void*)g,
                                   (__attribute__((address_space(3))) void*)l, 16, 0, 0);
}

#define VM4 asm volatile("s_waitcnt vmcnt(4)" ::: "memory")
#define VM2 asm volatile("s_waitcnt vmcnt(2)" ::: "memory")
#define VM0 asm volatile("s_waitcnt vmcnt(0)" ::: "memory")
#define LGKM0 asm volatile("s_waitcnt lgkmcnt(0)" ::: "memory")
#define SB0 __builtin_amdgcn_sched_barrier(0)
#define BAR __builtin_amdgcn_s_barrier()

// ---------------- fused fp32 -> bf16 conversion (one launch, 5 segments) -----
__global__ void cvt_all(const float* __restrict__ x,  const float* __restrict__ wq,
                        const float* __restrict__ wk, const float* __restrict__ wv,
                        const float* __restrict__ wo,
                        u16* __restrict__ xb,  u16* __restrict__ wqb,
                        u16* __restrict__ wkb, u16* __restrict__ wvb,
                        u16* __restrict__ wob){
  const int b = blockIdx.x;
  const float* in; u16* out; int base;
  if      (b <  8192){ in = x;  out = xb;  base = b; }
  else if (b < 24576){ in = wq; out = wqb; base = b - 8192; }
  else if (b < 28672){ in = wk; out = wkb; base = b - 24576; }
  else if (b < 32768){ in = wv; out = wvb; base = b - 28672; }
  else               { in = wo; out = wob; base = b - 32768; }
  const int i = (base*256 + threadIdx.x)*4;
  float4 v = *(const float4*)(in + i);
  ushort4 o;
  o.x = f2bf(v.x); o.y = f2bf(v.y); o.z = f2bf(v.z); o.w = f2bf(v.w);
  *(ushort4*)(out + i) = o;
}

// ---------------- out += partial (f32x4, exact grid) --------------------------
__global__ void add_f32(float* __restrict__ out, const float* __restrict__ p){
  const int i = blockIdx.x*256 + threadIdx.x;
  float4 a = ((const float4*)out)[i];
  const float4 b = ((const float4*)p)[i];
  a.x += b.x; a.y += b.y; a.z += b.z; a.w += b.w;
  ((float4*)out)[i] = a;
}

// ---------------- m201-style 4-phase pipelined NT GEMM ------------------------
// BM=256, BN=BUNITS*64 (192 or 256), BK=64, 8 waves (2x4), dbuf LDS, 1-deep
// prefetch. Per K-tile: 4 m-slice phases, each {ds_read 2 m-frags (+ all B at
// P0, held in regs) ; stage 1-2 64-row units ; counted VM ; BAR ; lgkm0+SB0 ;
// setprio'd MFMA ; BAR}. vmcnt only at end-P1 (4) and end-P3 (2) — loads never
// drain in the loop (T3+T4). T2 swizzle both-sides, T1 XCD swizzle, T5 setprio.
// EPI 0 (BUNITS=3): fused QKV, B = [wq;wk;wv] contiguous [6144][4096];
//   epilogue routes per 16-col frag: Q+RoPE / K+RoPE / V^T. grid 8x32=256.
// EPI 1 (BUNITS=4): O-proj split-K=2, f32 partials. grid 8x2x16=256.
template<int BUNITS, int EPI>
__global__ __launch_bounds__(512, 2) void gemmP(const u16* __restrict__ A,
    const u16* __restrict__ B, void* __restrict__ C0, void* __restrict__ C1,
    void* __restrict__ C2, const float* __restrict__ rf, float* __restrict__ Cp){
  constexpr int BN = BUNITS*64;
  __shared__ __align__(16) char lds[65536 + BUNITS*16384];  // A[2][256][128B] | B[2][BN][128B]
  const int t = threadIdx.x, w = t >> 6, l = t & 63;
  const int lg = l >> 4, li = l & 15;
  const int wr = w >> 2, wc = w & 3;
  const int idx = ((int)blockIdx.x & 7)*32 + ((int)blockIdx.x >> 3);  // XCD swizzle (nwg=256)

  int bm, bn, kbase, nt, ks = 0;
  if (EPI == 0){ bm = idx & 7; bn = idx >> 3; kbase = 0; nt = 64; }
  else         { bm = idx & 7; ks = (idx >> 3) & 1; bn = idx >> 4; kbase = ks*2048; nt = 32; }
  const u16* Ab = A + (size_t)bm*256*DIM;
  const u16* Bb = B + (size_t)bn*BN*DIM;

  // stage one 64-row x 128B unit: 1 load/thread (512 x 16B = 8KB)
  auto stA = [&](int k0, int abase, int u){
    const int r = u*64 + (t >> 3);
    gl_lds16(Ab + (size_t)r*DIM + k0 + (((t & 7) ^ (r & 7)) << 3),
             lds + abase + u*8192 + (t >> 3)*128 + (t & 7)*16);
  };
  auto stB = [&](int k0, int bbase, int u){
    const int r = u*64 + (t >> 3);
    gl_lds16(Bb + (size_t)r*DIM + k0 + (((t & 7) ^ (r & 7)) << 3),
             lds + bbase + u*8192 + (t >> 3)*128 + (t & 7)*16);
  };

  f32x4 acc[8][BUNITS] = {};
  bf16x8 bfr[BUNITS][2];   // B-frags held across all 4 phases of a tile

// phase p: ds_read m-frags 2p,2p+1 (+ all B at p==0); then __VA_ARGS__ (stages
// + counted VM); then BAR ; lgkm0 ; pinned setprio'd MFMA ; BAR.
#define PH(p, ...) { \
    bf16x8 af[2][2]; \
    _Pragma("unroll") \
    for (int q = 0; q < 2; ++q){ \
      const int R = wr*128 + (2*(p)+q)*16 + li; \
      af[q][0] = *(const bf16x8*)(ldsA + R*128 + (( lg    ^ (R & 7)) << 4)); \
      af[q][1] = *(const bf16x8*)(ldsA + R*128 + (((lg+4) ^ (R & 7)) << 4)); \
    } \
    if ((p) == 0){ \
      _Pragma("unroll") \
      for (int j = 0; j < BUNITS; ++j){ \
        const int R = wc*(BUNITS*16) + j*16 + li; \
        bfr[j][0] = *(const bf16x8*)(ldsB + R*128 + (( lg    ^ (R & 7)) << 4)); \
        bfr[j][1] = *(const bf16x8*)(ldsB + R*128 + (((lg+4) ^ (R & 7)) << 4)); \
      } \
    } \
    __VA_ARGS__; \
    BAR; LGKM0; SB0; \
    __builtin_amdgcn_s_setprio(1); \
    _Pragma("unroll") \
    for (int q = 0; q < 2; ++q) \
      _Pragma("unroll") \
      for (int j = 0; j < BUNITS; ++j){ \
        acc[2*(p)+q][j] = __builtin_amdgcn_mfma_f32_16x16x32_bf16(af[q][0], bfr[j][0], acc[2*(p)+q][j], 0, 0, 0); \
        acc[2*(p)+q][j] = __builtin_amdgcn_mfma_f32_16x16x32_bf16(af[q][1], bfr[j][1], acc[2*(p)+q][j], 0, 0, 0); \
      } \
    __builtin_amdgcn_s_setprio(0); \
    BAR; }

  // prologue: stage tile 0 in consumption order {A0,A2,B*,A1,A3}
  stA(kbase, 0, 0); stA(kbase, 0, 2);
  #pragma unroll
  for (int u = 0; u < BUNITS; ++u) stB(kbase, 65536, u);
  stA(kbase, 0, 1); stA(kbase, 0, 3);
  VM2; BAR;

  for (int tt = 0; tt < nt; ++tt){
    const int buf = tt & 1, b2 = buf ^ 1;
    const int k1 = kbase + (tt+1)*64;
    const bool pf = (tt + 1 < nt);
    const char* ldsA = lds + buf*32768;
    const char* ldsB = lds + 65536 + buf*BUNITS*8192;
    const int a2 = b2*32768, b2o = 65536 + b2*BUNITS*8192;

    PH(0, if (pf){ stA(k1, a2, 0); stA(k1, a2, 2); })
    PH(1, if (pf){ stB(k1, b2o, 0); stB(k1, b2o, 1); VM4; } else { VM0; })
    PH(2, if (pf){ if constexpr (BUNITS == 4){ stB(k1, b2o, 2); stB(k1, b2o, 3); }
                   else                      { stB(k1, b2o, 2); stA(k1, a2, 1); } })
    PH(3, if (pf){ if constexpr (BUNITS == 4){ stA(k1, a2, 1); stA(k1, a2, 3); }
                   else                      { stA(k1, a2, 3); }
                   VM2; })
  }
#undef PH

  // ---------------- epilogue ----------------
  if (EPI == 1){
    float* C = (float*)(ks ? Cp : C0);
    #pragma unroll
    for (int i = 0; i < 8; ++i){
      const int srow = bm*256 + wr*128 + i*16 + lg*4;
      #pragma unroll
      for (int j = 0; j < BUNITS; ++j){
        const int col = bn*BN + wc*(BUNITS*16) + j*16 + li;
        #pragma unroll
        for (int r = 0; r < 4; ++r)
          C[(size_t)(srow + r)*DIM + col] = acc[i][j][r];
      }
    }
  } else {
    #pragma unroll
    for (int i = 0; i < 8; ++i){
      const int srow0 = bm*256 + wr*128 + i*16 + lg*4;
      #pragma unroll
      for (int j = 0; j < BUNITS; ++j){
        const int fc0 = bn*BN + wc*(BUNITS*16) + j*16;   // frag base col (16-aligned)
        const int col = fc0 + li;
        if (fc0 < 5120){                   // Q (cols<4096) or K: fused RoPE
          u16* C  = (fc0 < 4096) ? (u16*)C0 : (u16*)C1;
          const int ldc  = (fc0 < 4096) ? DIM : KVD;
          const int ccol = (fc0 < 4096) ? col : col - 4096;
          const int i4 = ((col & 127) >> 1) << 2;        // boundaries %128==0
          #pragma unroll
          for (int r = 0; r < 4; ++r){
            const float v = acc[i][j][r];
            const float p = __shfl_xor(v, 1);            // partner col (li^1)
            const int srow = srow0 + r;
            const float cs = rf[(size_t)srow*256 + i4];
            const float sn = rf[(size_t)srow*256 + i4 + 1];
            const float o = (col & 1) ? (v*cs + p*sn) : (v*cs - p*sn);
            C[(size_t)srow*ldc + ccol] = f2bf(o);
          }
        } else {                           // V -> transposed write Vt[1024][2048]
          u16* C = (u16*)C2;
          ushort4 o;
          o.x = f2bf(acc[i][j][0]); o.y = f2bf(acc[i][j][1]);
          o.z = f2bf(acc[i][j][2]); o.w = f2bf(acc[i][j][3]);
          *(ushort4*)&C[(size_t)(col - 5120)*SEQ + srow0] = o;
        }
      }
    }
  }
}

// ---------------- causal GQA flash attention ---------------------------------
// 1D grid 1024, longest-qt blocks first: qt = 31 - bid/32, h = bid%32.
// 4 waves; wave w owns q rows [qt*64+16w, +16). Swapped QK^T (mfma(K,Q)) so
// each lane owns one full q-row (q = li): in-lane softmax + 2-shfl reduce.
// K/V double-buffered in LDS, next tile staged before compute (2-phase T3).
__global__ __launch_bounds__(256) void flash_attn(const u16* __restrict__ Q,
                                                  const u16* __restrict__ Kg,
                                                  const u16* __restrict__ Vt,
                                                  u16* __restrict__ O){
  __shared__ bf16x8 smK[2][64*16];              // [64 rows][16 slots], swizzled; 2x16KB
  __shared__ bf16x8 smV[2][128*8];              // [128 rows][8 slots], swizzled; 2x16KB
  __shared__ __align__(16) u16 smP[4][16*64];   // per-wave P, XOR-swizzled 16B chunks; 8KB
  const int bid = blockIdx.x;
  const int h  = bid & 31;
  const int qt = 31 - (bid >> 5);
  const int g  = h >> 2;
  const int t = threadIdx.x, w = t >> 6, l = t & 63;
  const int lg = l >> 4, li = l & 15;

  bf16x8 qf[4];                                  // Q row (w*16+li), d-chunks
  {
    const u16* qrow = Q + (size_t)(qt*64 + w*16 + li)*DIM + h*HD;
    #pragma unroll
    for (int kc = 0; kc < 4; ++kc)
      qf[kc] = *(const bf16x8*)(qrow + kc*32 + lg*8);
  }
  f32x4 accO[8] = {};
  float mrun = -1e30f, lsum = 0.f;
  const float SC = 0.08838834764831845f * 1.4426950408889634f;  // scale * log2(e)

  const int ksrow = t >> 4, ksslot = t & 15;  // K staging: 256B rows, 16 slots
  const int vsrow = t >> 3, vsslot = t & 7;   // V staging: 128B rows, 8 slots

  auto stage = [&](int kt, int b){
    #pragma unroll
    for (int j = 0; j < 4; ++j){
      const int krow = j*16 + ksrow;
      const int ksl = (ksslot & 8) | ((ksslot ^ (krow & 7)) & 7);
      gl_lds16(Kg + (size_t)(kt*64 + krow)*KVD + g*HD + ksl*8, (char*)&smK[b][0] + j*4096 + w*1024);
      const int vrow = j*32 + vsrow;
      const int vsl = (vsslot ^ (vrow & 7)) & 7;
      gl_lds16(Vt + (size_t)(g*HD + vrow)*SEQ + kt*64 + vsl*8, (char*)&smV[b][0] + j*4096 + w*1024);
    }
  };

  stage(0, 0);
  int buf = 0;
  u16* pw = &smP[w][0];

  for (int kt = 0; kt <= qt; ++kt){
    __syncthreads();                      // implicit vmcnt(0): tile-kt stage done
    if (kt < qt) stage(kt + 1, buf ^ 1);  // overlap next stage with this compute

    // S^T = K Q^T : lane holds S[kk = nj*16+lg*4+r][q = li]
    f32x4 sacc[4] = {};
    #pragma unroll
    for (int kc = 0; kc < 4; ++kc){
      #pragma unroll
      for (int nj = 0; nj < 4; ++nj){
        const int R = nj*16 + li;
        int sl = lg + 4*kc;
        sl = (sl & 8) | ((sl ^ (R & 7)) & 7);
        sacc[nj] = __builtin_amdgcn_mfma_f32_16x16x32_bf16(smK[buf][R*16 + sl], qf[kc], sacc[nj], 0, 0, 0);
      }
    }
    float p[4][4];
    #pragma unroll
    for (int nj = 0; nj < 4; ++nj)
      #pragma unroll
      for (int r = 0; r < 4; ++r)
        p[nj][r] = sacc[nj][r] * SC;
    if (kt == qt){                         // mask only on the diagonal tile
      const int qloc = w*16 + li;
      #pragma unroll
      for (int nj = 0; nj < 4; ++nj)
        #pragma unroll
        for (int r = 0; r < 4; ++r)
          if (nj*16 + lg*4 + r > qloc) p[nj][r] = -1e30f;
    }
    // online softmax, row q=li fully in this lane (16 vals) + lanes l^16,l^32
    float mx = p[0][0];
    #pragma unroll
    for (int nj = 0; nj < 4; ++nj)
      #pragma unroll
      for (int r = 0; r < 4; ++r) mx = fmaxf(mx, p[nj][r]);
    mx = fmaxf(mx, __shfl_xor(mx, 16));
    mx = fmaxf(mx, __shfl_xor(mx, 32));
    const float mnew = fmaxf(mrun, mx);
    const float alpha = exp2f(mrun - mnew);
    float s = 0.f;
    #pragma unroll
    for (int nj = 0; nj < 4; ++nj)
      #pragma unroll
      for (int r = 0; r < 4; ++r){ p[nj][r] = exp2f(p[nj][r] - mnew); s += p[nj][r]; }
    s += __shfl_xor(s, 16);
    s += __shfl_xor(s, 32);
    lsum = lsum * alpha + s;
    mrun = mnew;
    // broadcast alpha to accO's rows (q = lg*4+r held by lane li' = lg*4+r)
    float al[4];
    #pragma unroll
    for (int r = 0; r < 4; ++r) al[r] = __shfl(alpha, (l & 48) | (lg*4 + r));
    #pragma unroll
    for (int dj = 0; dj < 8; ++dj)
      #pragma unroll
      for (int r = 0; r < 4; ++r) accO[dj][r] *= al[r];
    // write P (row q=li, kk consecutive per write): 4x 8B swizzled ds_write
    #pragma unroll
    for (int nj = 0; nj < 4; ++nj){
      const int c = nj*2 + (lg >> 1);
      uint2 v; v.x = pack2bf(p[nj][0], p[nj][1]); v.y = pack2bf(p[nj][2], p[nj][3]);
      *(uint2*)((char*)pw + li*128 + ((c ^ (li & 7)) << 4) + ((lg & 1) << 3)) = v;
    }
    // O += P V   (A-frag: P row li, kk = kc2*32+lg*8+j; B-frag: Vt row d)
    #pragma unroll
    for (int kc2 = 0; kc2 < 2; ++kc2){
      const bf16x8 pf = *(const bf16x8*)((char*)pw + li*128 + (((kc2*4 + lg) ^ (li & 7)) << 4));
      #pragma unroll
      for (int dj = 0; dj < 8; ++dj){
        const int R = dj*16 + li;
        const bf16x8 vf = smV[buf][R*8 + ((lg + 4*kc2) ^ (R & 7))];
        accO[dj] = __builtin_amdgcn_mfma_f32_16x16x32_bf16(pf, vf, accO[dj], 0, 0, 0);
      }
    }
    buf ^= 1;
  }
  // epilogue: divide by row sum (row q=lg*4+r), write
  float linv[4];
  #pragma unroll
  for (int r = 0; r < 4; ++r) linv[r] = 1.f / __shfl(lsum, (l & 48) | (lg*4 + r));
  #pragma unroll
  for (int dj = 0; dj < 8; ++dj)
    #pragma unroll
    for (int r = 0; r < 4; ++r)
      O[(size_t)(qt*64 + w*16 + lg*4 + r)*DIM + h*HD + dj*16 + li] = f2bf(accO[dj][r] * linv[r]);
}

// -----------------------------------------------------------------------------
extern "C" void kernel_launch(void* const* d_in, const int* in_sizes, int n_in,
                              void* d_out, int out_size, void* d_ws, size_t ws_size,
                              hipStream_t stream){
  const float* x  = (const float*)d_in[0];
  const float* wq = (const float*)d_in[1];
  const float* wk = (const float*)d_in[2];
  const float* wv = (const float*)d_in[3];
  const float* wo = (const float*)d_in[4];
  const float* rf = (const float*)d_in[5];
  // d_in[6] = start_pos (unused by the reference)
  float* out = (float*)d_out;

  char* ws = (char*)d_ws;
  size_t off = 0;
  auto alloc = [&](size_t nbytes){ void* p = ws + off; off += (nbytes + 255) & ~(size_t)255; return p; };
  u16* xb  = (u16*)alloc((size_t)SEQ*DIM*2);
  u16* wqb = (u16*)alloc((size_t)DIM*DIM*2);   // wqb/wkb/wvb contiguous => B[6144][4096]
  u16* wkb = (u16*)alloc((size_t)KVD*DIM*2);
  u16* wvb = (u16*)alloc((size_t)KVD*DIM*2);
  u16* wob = (u16*)alloc((size_t)DIM*DIM*2);
  u16* Qb  = (u16*)alloc((size_t)SEQ*DIM*2);
  u16* K8  = (u16*)alloc((size_t)SEQ*KVD*2);
  u16* Vtr = (u16*)alloc((size_t)KVD*SEQ*2);
  u16* AO  = (u16*)alloc((size_t)SEQ*DIM*2);
  float* P1 = (float*)wqb;   // reuse: wqb is dead after the QKV GEMM (32 MB)

  cvt_all<<<49152, 256, 0, stream>>>(x, wq, wk, wv, wo, xb, wqb, wkb, wvb, wob);

  // Fused QKV projection + RoPE + V^T (256 blocks = 8bm x 32bn, BN=192)
  gemmP<3, 0><<<256, 512, 0, stream>>>(xb, wqb, Qb, K8, Vtr, rf, nullptr);

  flash_attn<<<SEQ/64 * NH, 256, 0, stream>>>(Qb, K8, Vtr, AO);

  // O projection, split-K=2 (256 blocks = 8bm x 2ks x 16bn, BN=256)
  gemmP<4, 1><<<256, 512, 0, stream>>>(AO, wob, out, nullptr, nullptr, nullptr, P1);
  add_f32<<<8192, 256, 0, stream>>>(out, P1);
}